// Round 7
// baseline (86.268 us; speedup 1.0000x reference)
//
#include <hip/hip_runtime.h>
#include <hip/hip_bf16.h>

// Problem constants (fixed by setup_inputs):
//   T=36, Q=2048, C=42 (num_classes=41), N=128
// Inputs (d_in order):
//   0: pred_logits  float32 [T*Q, C]
//   1: pred_boxes   float32 [T*Q, 4]   (cx,cy,w,h)
//   2: tgt_labels   int32   [N*T]
//   3: tgt_boxes    float32 [N*T, 4]
//   4: tgt_valid    int32   [N*T]
//   5: tgt_original_valid int32 [N*T]
// Output: float32 [Q, N] row-major, out[q*N+n]
//
// R7 = R6 (best: two kernels, bf16 P2, valid-skip + t-split) + pred_boxes
// staged ONCE per block in LDS. Previously each of the 8 waves re-loaded
// pb[t][q-tile] from L2 (~147 MB total); staging cuts it 4x (~37 MB).
// s_res is unioned into the s_pb buffer (dead after t-loop) to keep total
// LDS < 40 KB -> 4 blocks/CU = 32 waves/CU.

constexpr int T = 36;
constexpr int Q = 2048;
constexpr int C = 42;
constexpr int N = 128;

// ---------------------------------------------------------------------------
// Kernel 1: row softmax of logits, written TRANSPOSED as P2[t][c][q] (bf16).
// 4 threads per row in the reduction; exp computed once (stored in tile).
// Write pass pairs two q's per thread -> coalesced 4B bf16x2 stores.
// ---------------------------------------------------------------------------
__global__ __launch_bounds__(256) void softmax_transpose_kernel(
    const float* __restrict__ logits, __hip_bfloat16* __restrict__ P2) {
  constexpr int QB = 64;
  constexpr int LS = C + 1;  // 43: gcd(43,32)=1 -> conflict-free

  __shared__ float tile[QB * LS];
  __shared__ float s_max[4 * QB];
  __shared__ float s_sum[4 * QB];
  __shared__ float s_rinv[QB];

  const int t = blockIdx.y;
  const int q0 = blockIdx.x * QB;
  const int tid = threadIdx.x;

  const float* src = logits + ((size_t)t * Q + q0) * C;
  for (int i = tid; i < QB * C; i += 256) {
    int r = i / C, c = i % C;
    tile[r * LS + c] = src[i];
  }
  __syncthreads();

  // 4 threads per row: col ranges {0..10, 11..21, 22..31, 32..41}.
  const int part = tid >> 6;
  const int row = tid & 63;
  const int c0 = (part < 2) ? part * 11 : 22 + (part - 2) * 10;
  const int c1 = (part < 2) ? c0 + 11 : c0 + 10;

  float m = -1e30f;
  for (int c = c0; c < c1; ++c) m = fmaxf(m, tile[row * LS + c]);
  s_max[part * QB + row] = m;
  __syncthreads();

  m = fmaxf(fmaxf(s_max[row], s_max[QB + row]),
            fmaxf(s_max[2 * QB + row], s_max[3 * QB + row]));
  float s = 0.f;
  for (int c = c0; c < c1; ++c) {
    float e = __expf(tile[row * LS + c] - m);
    tile[row * LS + c] = e;  // single exp: reuse in the write pass
    s += e;
  }
  s_sum[part * QB + row] = s;
  __syncthreads();

  if (part == 0) {
    float stot = s_sum[row] + s_sum[QB + row] + s_sum[2 * QB + row] +
                 s_sum[3 * QB + row];
    s_rinv[row] = 1.f / stot;
  }
  __syncthreads();

  // Transposed write, two q's per thread -> coalesced 4B bf16x2 stores.
  for (int i = tid; i < QB * C / 2; i += 256) {
    int c = i >> 5;   // 0..41
    int r2 = i & 31;  // q-pair index
    float v0 = tile[(2 * r2) * LS + c] * s_rinv[2 * r2];
    float v1 = tile[(2 * r2 + 1) * LS + c] * s_rinv[2 * r2 + 1];
    __hip_bfloat162 pk;
    pk.x = __float2bfloat16(v0);
    pk.y = __float2bfloat16(v1);
    *(__hip_bfloat162*)(P2 + (size_t)(t * C + c) * Q + q0 + 2 * r2) = pk;
  }
}

// ---------------------------------------------------------------------------
// Kernel 2: cost[q,n] = sum_t valid*(l1 - prob - iou) / denom[n].
// Block 512 = 64 q x 4 n-subs x 2 t-halves (18 t each); grid (32,32) =
// 1024 blocks x 8 waves = 32 waves/CU. Wave-uniform valid-skip branch.
// pred_boxes staged once per block in LDS (36 KB, coalesced b128), removing
// the 4x redundant per-wave L2 re-reads. s_res reuses the s_pb buffer.
// ---------------------------------------------------------------------------
__global__ __launch_bounds__(512) void cost_kernel(
    const __hip_bfloat16* __restrict__ P2, const float* __restrict__ pred_boxes,
    const int* __restrict__ labels, const float* __restrict__ tboxes,
    const int* __restrict__ valid, const int* __restrict__ ovalid,
    float* __restrict__ out) {
  constexpr int NB = 4;
  constexpr int RS = NB + 1;  // stride 5: gcd(5,32)=1, conflict-free

  const int q0 = blockIdx.x * 64;
  const int n0 = blockIdx.y * NB;
  const int tid = threadIdx.x;     // 0..511
  const int lane = tid & 63;       // q offset
  const int sub = (tid >> 6) & 3;  // local n (wave-uniform)
  const int half = tid >> 8;       // t-half (wave-uniform)
  const int q = q0 + lane;

  // s_mem: [0, 36864) = s_pb (T*64 float4) during the t-loop;
  //        [0, 2*64*RS*4) = s_res after it (barrier-separated reuse).
  __shared__ __align__(16) char s_mem[T * 64 * 16];
  float4* s_pb = (float4*)s_mem;
  float* s_res = (float*)s_mem;

  __shared__ float4 s_tb[NB * T];
  __shared__ int s_idv[NB * T];  // (valid<<8) | id
  __shared__ float s_rden[NB];   // 1/denom

  // Stage pred_boxes for this q-tile, all t: 2304 float4 = 36 KB, coalesced.
  for (int i = tid; i < T * 64; i += 512) {
    int t = i >> 6, l = i & 63;
    s_pb[i] = ((const float4*)pred_boxes)[t * Q + q0 + l];
  }
  for (int i = tid; i < NB * T; i += 512) {
    int n = n0 + i / T;
    int t = i % T;
    int g = n * T + t;
    s_idv[i] = ((ovalid[g] == 0) ? (C - 1) : labels[g]) | (valid[g] << 8);
    s_tb[i] = ((const float4*)tboxes)[g];
  }
  if (tid < NB) {
    int n = n0 + tid;
    int s = 0;
    for (int t = 0; t < T; ++t) s += valid[n * T + t];
    s_rden[tid] = 1.f / (float)s;
  }
  __syncthreads();

  float acc = 0.f;
  const __hip_bfloat16* probs_base = P2 + q;
  const int t_begin = half * (T / 2);
  const int t_end = t_begin + (T / 2);

  for (int t = t_begin; t < t_end; ++t) {
    int pk = s_idv[sub * T + t];
    if (pk & 0x100) {  // wave-uniform: whole wave shares (n,t) -> no divergence
      float4 pb = s_pb[t * 64 + lane];  // LDS, conflict-free b128
      float4 tb = s_tb[sub * T + t];
      int id = pk & 0xff;
      // Coalesced gather: 64 lanes -> 64 consecutive bf16 (one 128B line).
      float p = __bfloat162float(probs_base[(size_t)(t * C + id) * Q]);

      float l1 = 0.25f * (fabsf(pb.x - tb.x) + fabsf(pb.y - tb.y) +
                          fabsf(pb.z - tb.z) + fabsf(pb.w - tb.w));
      float px1 = pb.x - 0.5f * pb.z, py1 = pb.y - 0.5f * pb.w;
      float px2 = pb.x + 0.5f * pb.z, py2 = pb.y + 0.5f * pb.w;
      float tx1 = tb.x - 0.5f * tb.z, ty1 = tb.y - 0.5f * tb.w;
      float tx2 = tb.x + 0.5f * tb.z, ty2 = tb.y + 0.5f * tb.w;
      float iw = fmaxf(fminf(px2, tx2) - fmaxf(px1, tx1), 0.f);
      float ih = fmaxf(fminf(py2, ty2) - fmaxf(py1, ty1), 0.f);
      float inter = iw * ih;
      float uni = pb.z * pb.w + tb.z * tb.w - inter;
      acc += l1 - p - inter / uni;
    }
  }

  // s_pb is dead; barrier, then reuse its space as s_res.
  __syncthreads();
  s_res[half * (64 * RS) + lane * RS + sub] = acc;
  __syncthreads();
  if (half == 0) {
    float tot = (acc + s_res[64 * RS + lane * RS + sub]) * s_rden[sub];
    s_res[lane * RS + sub] = tot;
  }
  __syncthreads();

  if (tid < 64) {
    float4 o;
    o.x = s_res[tid * RS + 0];
    o.y = s_res[tid * RS + 1];
    o.z = s_res[tid * RS + 2];
    o.w = s_res[tid * RS + 3];
    *(float4*)(out + (size_t)(q0 + tid) * N + n0) = o;
  }
}

extern "C" void kernel_launch(void* const* d_in, const int* in_sizes, int n_in,
                              void* d_out, int out_size, void* d_ws, size_t ws_size,
                              hipStream_t stream) {
  const float* logits = (const float*)d_in[0];
  const float* pboxes = (const float*)d_in[1];
  const int* labels = (const int*)d_in[2];
  const float* tboxes = (const float*)d_in[3];
  const int* valid = (const int*)d_in[4];
  const int* ovalid = (const int*)d_in[5];
  float* out = (float*)d_out;

  // Workspace: transposed bf16 probs P2[T][C][Q] = 36*42*2048*2 B = 6.2 MB.
  __hip_bfloat16* P2 = (__hip_bfloat16*)d_ws;

  dim3 g1(Q / 64, T);
  softmax_transpose_kernel<<<g1, 256, 0, stream>>>(logits, P2);

  dim3 g2(Q / 64, N / 4);
  cost_kernel<<<g2, 512, 0, stream>>>(P2, pboxes, labels, tboxes, valid, ovalid, out);
}